// Round 2
// baseline (9380.134 us; speedup 1.0000x reference)
//
#include <hip/hip_runtime.h>
#include <math.h>

#define DD 512
#define TM 20
#define TN 256
#define KC 16
#define KMAX 16
#define NBLKA 100

// ---------------- Kernel A1: partial column sums of x^2 (fp64, deterministic) ----------------
__global__ void colsum_partial(const float* __restrict__ x, double* __restrict__ partial,
                               int N, int rows_per_block) {
    int b = blockIdx.x;
    int t = threadIdx.x;                 // 256 threads, each owns cols t and t+256
    int r0 = b * rows_per_block;
    int r1 = min(r0 + rows_per_block, N);
    double s0 = 0.0, s1 = 0.0;
    for (int r = r0; r < r1; ++r) {
        float v0 = x[(size_t)r * DD + t];
        float v1 = x[(size_t)r * DD + t + 256];
        s0 += (double)v0 * (double)v0;
        s1 += (double)v1 * (double)v1;
    }
    partial[(size_t)b * DD + t]       = s0;
    partial[(size_t)b * DD + t + 256] = s1;
}

// ---------------- Kernel A2: finish — rn = 1/max(sqrt(s),eps), w = rn*rn (all fp64) ----------------
__global__ void colnorm_finish(const double* __restrict__ partial, double* __restrict__ rn,
                               double* __restrict__ w, int nblk) {
    int c = threadIdx.x;                 // 512 threads
    double s = 0.0;
    for (int b = 0; b < nblk; ++b) s += partial[(size_t)b * DD + c];
    double n = sqrt(s);
    n = fmax(n, 1e-12);
    double r = 1.0 / n;
    rn[c] = r;
    w[c]  = r * r;
}

// ---------------- Kernel B: sq[i] = fp64 sum_d (x*rn)^2 ----------------
__global__ void row_sq(const float* __restrict__ x, const double* __restrict__ rn,
                       double* __restrict__ sq, int N) {
    int i = blockIdx.x;
    int t = threadIdx.x;                 // 256 threads
    double a0 = (double)x[(size_t)i * DD + t]       * rn[t];
    double a1 = (double)x[(size_t)i * DD + t + 256] * rn[t + 256];
    double local = a0 * a0 + a1 * a1;

    __shared__ double red[256];
    red[t] = local;
    __syncthreads();
    for (int off = 128; off > 0; off >>= 1) {
        if (t < off) red[t] += red[t + off];
        __syncthreads();
    }
    if (t == 0) sq[i] = red[0];
}

// ---------------- Kernel C: exact fp64 Gram + fused per-row top-k (all-fp64 scores) ----------------
// g_ij = sum_d (x_i,d * w_d) * x_j,d   where w_d = rn_d^2  (== xn_i . xn_j to ~2e-16 rel)
__global__ __launch_bounds__(256) void gemm_topk(const float* __restrict__ x,
                                                 const double* __restrict__ w,
                                                 const double* __restrict__ sq,
                                                 int* __restrict__ out, int N, int k) {
    __shared__ float  Bt[KC][TN + 1];     // raw x_j values, transposed: 16*257*4 = 16448 B
    __shared__ double At[TM][KC + 1];     // x_i * w (fp64):             20*17*8  = 2720 B
    __shared__ double Sc[TM][TN + 1];     // fp64 scores:                20*257*8 = 41120 B
    __shared__ double sqi[TM];            // total ~60.4 KB

    int t    = threadIdx.x;               // thread t owns column j0+t
    int row0 = blockIdx.x * TM;

    if (t < TM) {
        int i = row0 + t;
        sqi[t] = (i < N) ? sq[i] : 0.0;
    }

    double acc[TM];
    double best_s[KMAX];
    int    best_j[KMAX];
#pragma unroll
    for (int r = 0; r < KMAX; ++r) { best_s[r] = __builtin_inf(); best_j[r] = 0x7fffffff; }

    int ntile = (N + TN - 1) / TN;
    for (int tile = 0; tile < ntile; ++tile) {
        int j0 = tile * TN;
#pragma unroll
        for (int ii = 0; ii < TM; ++ii) acc[ii] = 0.0;

        for (int kc = 0; kc < DD; kc += KC) {
            __syncthreads();   // previous chunk's LDS reads done before overwrite
            // stage B tile: 256*16 raw fp32, transpose-on-write, coalesced global reads
#pragma unroll
            for (int l = 0; l < (TN * KC) / 256; ++l) {
                int e  = t + l * 256;
                int kk = e % KC;
                int jj = e / KC;
                int j  = j0 + jj;
                Bt[kk][jj] = (j < N) ? x[(size_t)j * DD + kc + kk] : 0.f;
            }
            // stage A tile: 20*16 fp64 = x_i * w_d
            for (int e = t; e < TM * KC; e += 256) {
                int kk = e % KC;
                int ii = e / KC;
                int i  = row0 + ii;
                At[ii][kk] = (i < N) ? (double)x[(size_t)i * DD + kc + kk] * w[kc + kk] : 0.0;
            }
            __syncthreads();
            // fp64 accumulation
#pragma unroll 4
            for (int kk = 0; kk < KC; ++kk) {
                double b = (double)Bt[kk][t];
#pragma unroll
                for (int ii = 0; ii < TM; ++ii)
                    acc[ii] = fma(At[ii][kk], b, acc[ii]);
            }
        }
        // fp64 scores: s = (sq_i - 2*g) + sq_j
        int    j   = j0 + t;
        bool   jok = (j < N);
        double sqj = jok ? sq[j] : 0.0;
#pragma unroll
        for (int ii = 0; ii < TM; ++ii) {
            double g = acc[ii];
            double s = (sqi[ii] - 2.0 * g) + sqj;
            Sc[ii][t] = jok ? s : __builtin_inf();
        }
        __syncthreads();
        // per-row top-k scan; comparator matches top_k (value asc, then lower index)
        if (t < TM) {
            for (int c = 0; c < TN; ++c) {
                double s  = Sc[t][c];
                int    cj = j0 + c;
                double ws = best_s[k - 1];
                int    wj = best_j[k - 1];
                bool better = (s < ws) || (s == ws && cj < wj);
                if (better) {
                    int pos = k - 1;
                    while (pos > 0) {
                        double ps = best_s[pos - 1];
                        int    pj = best_j[pos - 1];
                        bool b2 = (s < ps) || (s == ps && cj < pj);
                        if (!b2) break;
                        best_s[pos] = ps; best_j[pos] = pj;
                        --pos;
                    }
                    best_s[pos] = s; best_j[pos] = cj;
                }
            }
        }
        __syncthreads();
    }
    // epilogue: edge_idx[0] = nn_idx, edge_idx[1] = center_idx
    if (t < TM) {
        int i = row0 + t;
        if (i < N) {
            size_t base = (size_t)i * k;
            for (int r = 0; r < k; ++r) {
                out[base + r]                 = best_j[r];
                out[(size_t)N * k + base + r] = i;
            }
        }
    }
}

extern "C" void kernel_launch(void* const* d_in, const int* in_sizes, int n_in,
                              void* d_out, int out_size, void* d_ws, size_t ws_size,
                              hipStream_t stream) {
    const float* x = (const float*)d_in[0];
    int N = in_sizes[0] / DD;            // 10000
    int k = out_size / (2 * N);          // 9
    if (k > KMAX) k = KMAX;

    char* ws = (char*)d_ws;
    double* partial = (double*)ws;                       // 100*512*8 = 409600 B
    double* rn      = (double*)(ws + 409600);            // 512*8     = 4096 B
    double* w       = (double*)(ws + 413696);            // 512*8     = 4096 B
    double* sq      = (double*)(ws + 417792);            // N*8       = 80000 B

    int rpb = (N + NBLKA - 1) / NBLKA;
    hipLaunchKernelGGL(colsum_partial, dim3(NBLKA), dim3(256), 0, stream, x, partial, N, rpb);
    hipLaunchKernelGGL(colnorm_finish, dim3(1), dim3(512), 0, stream, partial, rn, w, NBLKA);
    hipLaunchKernelGGL(row_sq, dim3(N), dim3(256), 0, stream, x, rn, sq, N);

    int nblk = (N + TM - 1) / TM;        // 500 blocks
    hipLaunchKernelGGL(gemm_topk, dim3(nblk), dim3(256), 0, stream, x, w, sq, (int*)d_out, N, k);
}

// Round 3
// 3998.927 us; speedup vs baseline: 2.3457x; 2.3457x over previous
//
#include <hip/hip_runtime.h>
#include <math.h>

#define DD 512
#define NBLKA 100

#define PM 128          // prefilter tile rows
#define PN 128          // prefilter tile cols
#define PKC 16          // k-chunk
#define CSPLIT 6        // column splits (6*79-tile sweep -> 474 blocks)
#define NC 16           // candidates kept per row per split
#define PBUF 16         // push buffer per row
#define NCTOT (CSPLIT*NC)   // 96 candidates per row total
#define KOUTMAX 16

// ---------------- Kernel A1: partial column sums of x^2 (fp64, deterministic) ----------------
__global__ void colsum_partial(const float* __restrict__ x, double* __restrict__ partial,
                               int N, int rows_per_block) {
    int b = blockIdx.x;
    int t = threadIdx.x;
    int r0 = b * rows_per_block;
    int r1 = min(r0 + rows_per_block, N);
    double s0 = 0.0, s1 = 0.0;
    for (int r = r0; r < r1; ++r) {
        float v0 = x[(size_t)r * DD + t];
        float v1 = x[(size_t)r * DD + t + 256];
        s0 += (double)v0 * (double)v0;
        s1 += (double)v1 * (double)v1;
    }
    partial[(size_t)b * DD + t]       = s0;
    partial[(size_t)b * DD + t + 256] = s1;
}

// ---------------- Kernel A2: rn=1/max(sqrt(s),eps) fp64, w=rn*rn fp64, rnf fp32 ----------------
__global__ void colnorm_finish(const double* __restrict__ partial, double* __restrict__ rn,
                               double* __restrict__ w, float* __restrict__ rnf, int nblk) {
    int c = threadIdx.x;                 // 512 threads
    double s = 0.0;
    for (int b = 0; b < nblk; ++b) s += partial[(size_t)b * DD + c];
    double n = fmax(sqrt(s), 1e-12);
    double r = 1.0 / n;
    rn[c]  = r;
    w[c]   = r * r;
    rnf[c] = (float)r;
}

// ---------------- Kernel B: sq[i] (fp64) and sqf[i] (fp32) ----------------
__global__ void row_sq(const float* __restrict__ x, const double* __restrict__ rn,
                       double* __restrict__ sq, float* __restrict__ sqf, int N) {
    int i = blockIdx.x;
    int t = threadIdx.x;
    double a0 = (double)x[(size_t)i * DD + t]       * rn[t];
    double a1 = (double)x[(size_t)i * DD + t + 256] * rn[t + 256];
    double local = a0 * a0 + a1 * a1;
    __shared__ double red[256];
    red[t] = local;
    __syncthreads();
    for (int off = 128; off > 0; off >>= 1) {
        if (t < off) red[t] += red[t + off];
        __syncthreads();
    }
    if (t == 0) { sq[i] = red[0]; sqf[i] = (float)red[0]; }
}

// ---------------- Kernel C: fp32 128x128 GEMM prefilter + per-row top-16 ----------------
__global__ __launch_bounds__(256, 2) void gemm_prefilter(
    const float* __restrict__ x, const float* __restrict__ rnf,
    const float* __restrict__ sqf, int* __restrict__ cand, int N, int ntileN)
{
    __shared__ float A_s[PKC][PM + 4];     // 8448 B  (xn rows, transposed)
    __shared__ float B_s[PKC][PN + 4];     // 8448 B  (xn cols, transposed)
    __shared__ float rnf_s[DD];            // 2048 B
    __shared__ float sqi_s[PM];
    __shared__ float sqj_s[PN];
    __shared__ float Ls[PM][NC + 1];       // 8704 B  sorted top-16 scores
    __shared__ int   Li[PM][NC + 1];       // 8704 B  sorted top-16 indices
    __shared__ float Bsc[PM][PBUF + 1];    // 8704 B  push buffer scores
    __shared__ int   Bid[PM][PBUF + 1];    // 8704 B  push buffer indices
    __shared__ float thr_s[PM];
    __shared__ int   cnt_s[PM];
    __shared__ int   again_s;

    int t  = threadIdx.x;
    int tx = t & 15, ty = t >> 4;
    int row0  = blockIdx.x * PM;
    int split = blockIdx.y;

    rnf_s[t]       = rnf[t];
    rnf_s[t + 256] = rnf[t + 256];
    if (t < PM) {
        int i = row0 + t;
        sqi_s[t] = (i < N) ? sqf[i] : 0.f;
        thr_s[t] = __builtin_inff();
        cnt_s[t] = 0;
        for (int m = 0; m < NC; ++m) { Ls[t][m] = __builtin_inff(); Li[t][m] = 0x7fffffff; }
    }

    float acc[8][8];

    for (int tile = split; tile < ntileN; tile += CSPLIT) {
        int col0 = tile * PN;
        __syncthreads();
        if (t < PN) {
            int j = col0 + t;
            sqj_s[t] = (j < N) ? sqf[j] : __builtin_inff();
        }
#pragma unroll
        for (int a = 0; a < 8; ++a)
#pragma unroll
            for (int b = 0; b < 8; ++b) acc[a][b] = 0.f;

#pragma unroll 1
        for (int kc = 0; kc < DD; kc += PKC) {
            __syncthreads();
#pragma unroll
            for (int l = 0; l < 2; ++l) {
                int idx = t + l * 256;
                int r = idx >> 2, g = idx & 3;
                float4 rv = *(const float4*)&rnf_s[kc + g * 4];
                int gi = row0 + r;
                float4 av = (gi < N) ? *(const float4*)&x[(size_t)gi * DD + kc + g * 4]
                                     : make_float4(0.f, 0.f, 0.f, 0.f);
                A_s[g * 4 + 0][r] = av.x * rv.x;
                A_s[g * 4 + 1][r] = av.y * rv.y;
                A_s[g * 4 + 2][r] = av.z * rv.z;
                A_s[g * 4 + 3][r] = av.w * rv.w;
                int gj = col0 + r;
                float4 bv = (gj < N) ? *(const float4*)&x[(size_t)gj * DD + kc + g * 4]
                                     : make_float4(0.f, 0.f, 0.f, 0.f);
                B_s[g * 4 + 0][r] = bv.x * rv.x;
                B_s[g * 4 + 1][r] = bv.y * rv.y;
                B_s[g * 4 + 2][r] = bv.z * rv.z;
                B_s[g * 4 + 3][r] = bv.w * rv.w;
            }
            __syncthreads();
#pragma unroll
            for (int kk = 0; kk < PKC; ++kk) {
                float4 a0 = *(const float4*)&A_s[kk][ty * 8];
                float4 a1 = *(const float4*)&A_s[kk][ty * 8 + 4];
                float4 b0 = *(const float4*)&B_s[kk][tx * 8];
                float4 b1 = *(const float4*)&B_s[kk][tx * 8 + 4];
                float ar[8] = {a0.x, a0.y, a0.z, a0.w, a1.x, a1.y, a1.z, a1.w};
                float br[8] = {b0.x, b0.y, b0.z, b0.w, b1.x, b1.y, b1.z, b1.w};
#pragma unroll
                for (int ri = 0; ri < 8; ++ri)
#pragma unroll
                    for (int ci = 0; ci < 8; ++ci)
                        acc[ri][ci] = fmaf(ar[ri], br[ci], acc[ri][ci]);
            }
        }
        // scores in place: s = (sq_i - 2g) + sq_j  (fp32; prefilter only)
#pragma unroll
        for (int ri = 0; ri < 8; ++ri)
#pragma unroll
            for (int ci = 0; ci < 8; ++ci)
                acc[ri][ci] = (sqi_s[ty * 8 + ri] - 2.f * acc[ri][ci]) + sqj_s[tx * 8 + ci];

        // candidate mask: below current row threshold and valid column
        unsigned long long rem = 0ull;
#pragma unroll
        for (int ri = 0; ri < 8; ++ri) {
            float th = thr_s[ty * 8 + ri];
#pragma unroll
            for (int ci = 0; ci < 8; ++ci) {
                int j = col0 + tx * 8 + ci;
                if (j < N && acc[ri][ci] < th)
                    rem |= 1ull << (ri * 8 + ci);
            }
        }
        // push/merge rounds until all candidates stored or dropped
        for (;;) {
            if (t == 0) again_s = 0;
            __syncthreads();
            if (rem) {
                unsigned long long mm = rem;
                while (mm) {
                    int bit = __builtin_ctzll(mm);
                    mm &= mm - 1;
                    int ri = bit >> 3, ci = bit & 7;
                    int r = ty * 8 + ri;
                    float s = acc[ri][ci];
                    if (!(s < thr_s[r])) { rem &= ~(1ull << bit); continue; }
                    int pos = atomicAdd(&cnt_s[r], 1);
                    if (pos < PBUF) {
                        Bsc[r][pos] = s;
                        Bid[r][pos] = col0 + tx * 8 + ci;
                        rem &= ~(1ull << bit);
                    }
                }
                if (rem) again_s = 1;
            }
            __syncthreads();
            if (t < PM) {
                int c = cnt_s[t]; if (c > PBUF) c = PBUF;
                cnt_s[t] = 0;
                for (int m = 0; m < c; ++m) {
                    float s = Bsc[t][m];
                    int   j = Bid[t][m];
                    float ws = Ls[t][NC - 1]; int wj = Li[t][NC - 1];
                    if (s < ws || (s == ws && j < wj)) {
                        int pos = NC - 1;
                        while (pos > 0) {
                            float ps = Ls[t][pos - 1]; int pj = Li[t][pos - 1];
                            if (!(s < ps || (s == ps && j < pj))) break;
                            Ls[t][pos] = ps; Li[t][pos] = pj;
                            --pos;
                        }
                        Ls[t][pos] = s; Li[t][pos] = j;
                    }
                }
                thr_s[t] = Ls[t][NC - 1];
            }
            __syncthreads();
            if (!again_s) break;
        }
    }
    // write this split's 16 candidates per row
    if (t < PM) {
        int i = row0 + t;
        if (i < N) {
            for (int m = 0; m < NC; ++m)
                cand[(size_t)i * NCTOT + split * NC + m] = Li[t][m];
        }
    }
}

// ---------------- Kernel D: exact fp64 rescore of 96 candidates/row + top-k ----------------
__global__ __launch_bounds__(256) void rescore_topk(
    const float* __restrict__ x, const double* __restrict__ w,
    const double* __restrict__ sq, const int* __restrict__ cand,
    int* __restrict__ out, int N, int k)
{
    int lane = threadIdx.x & 63;
    int wid  = threadIdx.x >> 6;
    int i = blockIdx.x * 4 + wid;
    if (i >= N) return;

    double aw[8];
#pragma unroll
    for (int c = 0; c < 8; ++c) {
        int d = lane + 64 * c;
        aw[c] = (double)x[(size_t)i * DD + d] * w[d];   // xn_i[d]^2-folded weight (round-2-validated math)
    }
    double sqi = sq[i];

    double bs[KOUTMAX];
    int    bj[KOUTMAX];
    for (int r = 0; r < k; ++r) { bs[r] = __builtin_inf(); bj[r] = 0x7fffffff; }

    for (int m = 0; m < NCTOT; ++m) {
        int j = cand[(size_t)i * NCTOT + m];
        double dot = 0.0;
#pragma unroll
        for (int c = 0; c < 8; ++c)
            dot = fma(aw[c], (double)x[(size_t)j * DD + lane + 64 * c], dot);
#pragma unroll
        for (int off = 32; off > 0; off >>= 1)
            dot += __shfl_xor(dot, off, 64);
        double s = (sqi - 2.0 * dot) + sq[j];
        // all lanes run identical insertion (dot is broadcast) — no divergence
        if (s < bs[k - 1] || (s == bs[k - 1] && j < bj[k - 1])) {
            int pos = k - 1;
            while (pos > 0) {
                double ps = bs[pos - 1]; int pj = bj[pos - 1];
                if (!(s < ps || (s == ps && j < pj))) break;
                bs[pos] = ps; bj[pos] = pj;
                --pos;
            }
            bs[pos] = s; bj[pos] = j;
        }
    }
    if (lane == 0) {
        for (int r = 0; r < k; ++r) {
            out[(size_t)i * k + r]               = bj[r];
            out[(size_t)N * k + (size_t)i * k + r] = i;
        }
    }
}

extern "C" void kernel_launch(void* const* d_in, const int* in_sizes, int n_in,
                              void* d_out, int out_size, void* d_ws, size_t ws_size,
                              hipStream_t stream) {
    const float* x = (const float*)d_in[0];
    int N = in_sizes[0] / DD;            // 10000
    int k = out_size / (2 * N);          // 9
    if (k > KOUTMAX) k = KOUTMAX;

    char* ws = (char*)d_ws;
    double* partial = (double*)ws;                        // 409600 B
    double* rn      = (double*)(ws + 409600);             // 4096 B
    double* w       = (double*)(ws + 413696);             // 4096 B
    float*  rnf     = (float*) (ws + 417792);             // 2048 B
    double* sq      = (double*)(ws + 419840);             // 80000 B
    float*  sqf     = (float*) (ws + 499840);             // 40000 B
    int*    cand    = (int*)   (ws + 539840);             // N*96*4 = 3.84 MB

    int rpb = (N + NBLKA - 1) / NBLKA;
    hipLaunchKernelGGL(colsum_partial, dim3(NBLKA), dim3(256), 0, stream, x, partial, N, rpb);
    hipLaunchKernelGGL(colnorm_finish, dim3(1), dim3(512), 0, stream, partial, rn, w, rnf, NBLKA);
    hipLaunchKernelGGL(row_sq, dim3(N), dim3(256), 0, stream, x, rn, sq, sqf, N);

    int nrow = (N + PM - 1) / PM;        // 79
    int ncol = (N + PN - 1) / PN;        // 79
    hipLaunchKernelGGL(gemm_prefilter, dim3(nrow, CSPLIT), dim3(256), 0, stream,
                       x, rnf, sqf, cand, N, ncol);

    hipLaunchKernelGGL(rescore_topk, dim3((N + 3) / 4), dim3(256), 0, stream,
                       x, w, sq, cand, (int*)d_out, N, k);
}

// Round 5
// 2544.954 us; speedup vs baseline: 3.6858x; 1.5713x over previous
//
#include <hip/hip_runtime.h>
#include <math.h>

#define DD 512
#define NBLKA 100

#define PM 128          // prefilter tile rows
#define PN 128          // prefilter tile cols
#define PKC 16          // k-chunk
#define CSPLIT 6        // column splits
#define NC 16           // candidates kept per row per split
#define PBUF 16         // push buffer per row
#define NCTOT (CSPLIT*NC)   // 96 candidates per row total
#define KOUTMAX 16

// ---------------- Kernel A1: partial column sums of x^2 (fp64, deterministic) ----------------
__global__ void colsum_partial(const float* __restrict__ x, double* __restrict__ partial,
                               int N, int rows_per_block) {
    int b = blockIdx.x;
    int t = threadIdx.x;
    int r0 = b * rows_per_block;
    int r1 = min(r0 + rows_per_block, N);
    double s0 = 0.0, s1 = 0.0;
    for (int r = r0; r < r1; ++r) {
        float v0 = x[(size_t)r * DD + t];
        float v1 = x[(size_t)r * DD + t + 256];
        s0 += (double)v0 * (double)v0;
        s1 += (double)v1 * (double)v1;
    }
    partial[(size_t)b * DD + t]       = s0;
    partial[(size_t)b * DD + t + 256] = s1;
}

// ---------------- Kernel A2: rn=1/max(sqrt(s),eps) fp64, w=rn*rn fp64, rnf fp32 ----------------
__global__ void colnorm_finish(const double* __restrict__ partial, double* __restrict__ rn,
                               double* __restrict__ w, float* __restrict__ rnf, int nblk) {
    int c = threadIdx.x;                 // 512 threads
    double s = 0.0;
    for (int b = 0; b < nblk; ++b) s += partial[(size_t)b * DD + c];
    double n = fmax(sqrt(s), 1e-12);
    double r = 1.0 / n;
    rn[c]  = r;
    w[c]   = r * r;
    rnf[c] = (float)r;
}

// ---------------- Kernel B: sq[i] (fp64) and sqf[i] (fp32) ----------------
__global__ void row_sq(const float* __restrict__ x, const double* __restrict__ rn,
                       double* __restrict__ sq, float* __restrict__ sqf, int N) {
    int i = blockIdx.x;
    int t = threadIdx.x;
    double a0 = (double)x[(size_t)i * DD + t]       * rn[t];
    double a1 = (double)x[(size_t)i * DD + t + 256] * rn[t + 256];
    double local = a0 * a0 + a1 * a1;
    __shared__ double red[256];
    red[t] = local;
    __syncthreads();
    for (int off = 128; off > 0; off >>= 1) {
        if (t < off) red[t] += red[t + off];
        __syncthreads();
    }
    if (t == 0) { sq[i] = red[0]; sqf[i] = (float)red[0]; }
}

// ---------------- Kernel C: fp32 128x128 GEMM prefilter + per-row top-16 ----------------
// Selection: static-indexed done-mask rescan (no scratch spill) + race-free
// 4-barrier retry-flag protocol.
__global__ __launch_bounds__(256, 2) void gemm_prefilter(
    const float* __restrict__ x, const float* __restrict__ rnf,
    const float* __restrict__ sqf, int* __restrict__ cand, int N, int ntileN)
{
    __shared__ float A_s[PKC][PM + 4];
    __shared__ float B_s[PKC][PN + 4];
    __shared__ float rnf_s[DD];
    __shared__ float sqi_s[PM];
    __shared__ float sqj_s[PN];
    __shared__ float Ls[PM][NC + 1];
    __shared__ int   Li[PM][NC + 1];
    __shared__ float Bsc[PM][PBUF + 1];
    __shared__ int   Bid[PM][PBUF + 1];
    __shared__ float thr_s[PM];
    __shared__ int   cnt_s[PM];
    __shared__ int   flag_s;

    int t  = threadIdx.x;
    int tx = t & 15, ty = t >> 4;
    int row0  = blockIdx.x * PM;
    int split = blockIdx.y;

    rnf_s[t]       = rnf[t];
    rnf_s[t + 256] = rnf[t + 256];
    if (t == 0) flag_s = 0;
    if (t < PM) {
        int i = row0 + t;
        sqi_s[t] = (i < N) ? sqf[i] : 0.f;
        thr_s[t] = __builtin_inff();
        cnt_s[t] = 0;
        for (int m = 0; m < NC; ++m) { Ls[t][m] = __builtin_inff(); Li[t][m] = 0x7fffffff; }
    }

    float acc[8][8];

    for (int tile = split; tile < ntileN; tile += CSPLIT) {
        int col0 = tile * PN;
        __syncthreads();
        if (t < PN) {
            int j = col0 + t;
            sqj_s[t] = (j < N) ? sqf[j] : __builtin_inff();
        }
#pragma unroll
        for (int a = 0; a < 8; ++a)
#pragma unroll
            for (int b = 0; b < 8; ++b) acc[a][b] = 0.f;

#pragma unroll 1
        for (int kc = 0; kc < DD; kc += PKC) {
            __syncthreads();
#pragma unroll
            for (int l = 0; l < 2; ++l) {
                int idx = t + l * 256;
                int r = idx >> 2, g = idx & 3;
                float4 rv = *(const float4*)&rnf_s[kc + g * 4];
                int gi = row0 + r;
                float4 av = (gi < N) ? *(const float4*)&x[(size_t)gi * DD + kc + g * 4]
                                     : make_float4(0.f, 0.f, 0.f, 0.f);
                A_s[g * 4 + 0][r] = av.x * rv.x;
                A_s[g * 4 + 1][r] = av.y * rv.y;
                A_s[g * 4 + 2][r] = av.z * rv.z;
                A_s[g * 4 + 3][r] = av.w * rv.w;
                int gj = col0 + r;
                float4 bv = (gj < N) ? *(const float4*)&x[(size_t)gj * DD + kc + g * 4]
                                     : make_float4(0.f, 0.f, 0.f, 0.f);
                B_s[g * 4 + 0][r] = bv.x * rv.x;
                B_s[g * 4 + 1][r] = bv.y * rv.y;
                B_s[g * 4 + 2][r] = bv.z * rv.z;
                B_s[g * 4 + 3][r] = bv.w * rv.w;
            }
            __syncthreads();
#pragma unroll
            for (int kk = 0; kk < PKC; ++kk) {
                float4 a0 = *(const float4*)&A_s[kk][ty * 8];
                float4 a1 = *(const float4*)&A_s[kk][ty * 8 + 4];
                float4 b0 = *(const float4*)&B_s[kk][tx * 8];
                float4 b1 = *(const float4*)&B_s[kk][tx * 8 + 4];
                float ar[8] = {a0.x, a0.y, a0.z, a0.w, a1.x, a1.y, a1.z, a1.w};
                float br[8] = {b0.x, b0.y, b0.z, b0.w, b1.x, b1.y, b1.z, b1.w};
#pragma unroll
                for (int ri = 0; ri < 8; ++ri)
#pragma unroll
                    for (int ci = 0; ci < 8; ++ci)
                        acc[ri][ci] = fmaf(ar[ri], br[ci], acc[ri][ci]);
            }
        }
        // scores in place: s = (sq_i - 2g) + sq_j  (fp32; prefilter only)
#pragma unroll
        for (int ri = 0; ri < 8; ++ri)
#pragma unroll
            for (int ci = 0; ci < 8; ++ci)
                acc[ri][ci] = (sqi_s[ty * 8 + ri] - 2.f * acc[ri][ci]) + sqj_s[tx * 8 + ci];

        // ---- push/merge rounds; static acc indexing; race-free flag protocol ----
        // invariant at loop top: flag_s == 0 and all threads share a common barrier
        unsigned long long done = 0ull;   // bit set = handled (stored or rejected)
        for (;;) {
            // PUSH phase
#pragma unroll
            for (int ri = 0; ri < 8; ++ri) {
                float th = thr_s[ty * 8 + ri];
#pragma unroll
                for (int ci = 0; ci < 8; ++ci) {
                    const unsigned long long bit = 1ull << (ri * 8 + ci);
                    if (!(done & bit)) {
                        float s = acc[ri][ci];
                        int   j = col0 + tx * 8 + ci;
                        if (j < N && s <= th) {
                            int pos = atomicAdd(&cnt_s[ty * 8 + ri], 1);
                            if (pos < PBUF) {
                                Bsc[ty * 8 + ri][pos] = s;
                                Bid[ty * 8 + ri][pos] = j;
                                done |= bit;
                            }
                        } else {
                            done |= bit;   // threshold only tightens -> final reject
                        }
                    }
                }
            }
            if (done != ~0ull) flag_s = 1;   // benign same-value race
            __syncthreads();                 // B1: buffer + flag visible
            // MERGE phase
            if (t < PM) {
                int c = cnt_s[t];
                if (c > PBUF) c = PBUF;
                cnt_s[t] = 0;
                for (int m = 0; m < c; ++m) {
                    float s = Bsc[t][m];
                    int   j = Bid[t][m];
                    float ws = Ls[t][NC - 1]; int wj = Li[t][NC - 1];
                    if (s < ws || (s == ws && j < wj)) {
                        int pos = NC - 1;
                        while (pos > 0) {
                            float ps = Ls[t][pos - 1]; int pj = Li[t][pos - 1];
                            if (!(s < ps || (s == ps && j < pj))) break;
                            Ls[t][pos] = ps; Li[t][pos] = pj;
                            --pos;
                        }
                        Ls[t][pos] = s; Li[t][pos] = j;
                    }
                }
                thr_s[t] = Ls[t][NC - 1];
            }
            __syncthreads();                 // B2: merge results visible
            int go = flag_s;
            __syncthreads();                 // B3: all reads of flag done
            if (t == 0) flag_s = 0;
            __syncthreads();                 // B4: reset visible before next writes
            if (!go) break;                  // uniform across the block
        }
    }
    // write this split's 16 candidates per row
    if (t < PM) {
        int i = row0 + t;
        if (i < N) {
            for (int m = 0; m < NC; ++m)
                cand[(size_t)i * NCTOT + split * NC + m] = Li[t][m];
        }
    }
}

// ---------------- Kernel D: exact fp64 rescore of 96 candidates/row + top-k ----------------
__global__ __launch_bounds__(256) void rescore_topk(
    const float* __restrict__ x, const double* __restrict__ w,
    const double* __restrict__ sq, const int* __restrict__ cand,
    int* __restrict__ out, int N, int k)
{
    int lane = threadIdx.x & 63;
    int wid  = threadIdx.x >> 6;
    int i = blockIdx.x * 4 + wid;
    if (i >= N) return;

    double aw[8];
#pragma unroll
    for (int c = 0; c < 8; ++c) {
        int d = lane + 64 * c;
        aw[c] = (double)x[(size_t)i * DD + d] * w[d];
    }
    double sqi = sq[i];

    double bs[KOUTMAX];
    int    bj[KOUTMAX];
    for (int r = 0; r < k; ++r) { bs[r] = __builtin_inf(); bj[r] = 0x7fffffff; }

    size_t base = (size_t)i * NCTOT;
    for (int m = 0; m < NCTOT; m += 2) {
        int j0 = cand[base + m];
        int j1 = cand[base + m + 1];
        const float* p0 = &x[(size_t)j0 * DD + lane];
        const float* p1 = &x[(size_t)j1 * DD + lane];
        float v0[8], v1[8];
#pragma unroll
        for (int c = 0; c < 8; ++c) v0[c] = p0[64 * c];
#pragma unroll
        for (int c = 0; c < 8; ++c) v1[c] = p1[64 * c];
        double d0 = 0.0, d1 = 0.0;
#pragma unroll
        for (int c = 0; c < 8; ++c) d0 = fma(aw[c], (double)v0[c], d0);
#pragma unroll
        for (int c = 0; c < 8; ++c) d1 = fma(aw[c], (double)v1[c], d1);
#pragma unroll
        for (int off = 32; off > 0; off >>= 1) {
            d0 += __shfl_xor(d0, off, 64);
            d1 += __shfl_xor(d1, off, 64);
        }
        double s0 = (sqi - 2.0 * d0) + sq[j0];
        double s1 = (sqi - 2.0 * d1) + sq[j1];
#pragma unroll 1
        for (int pick = 0; pick < 2; ++pick) {
            double s = pick ? s1 : s0;
            int    j = pick ? j1 : j0;
            if (s < bs[k - 1] || (s == bs[k - 1] && j < bj[k - 1])) {
                int pos = k - 1;
                while (pos > 0) {
                    double ps = bs[pos - 1]; int pj = bj[pos - 1];
                    if (!(s < ps || (s == ps && j < pj))) break;
                    bs[pos] = ps; bj[pos] = pj;
                    --pos;
                }
                bs[pos] = s; bj[pos] = j;
            }
        }
    }
    if (lane == 0) {
        for (int r = 0; r < k; ++r) {
            out[(size_t)i * k + r]                 = bj[r];
            out[(size_t)N * k + (size_t)i * k + r] = i;
        }
    }
}

extern "C" void kernel_launch(void* const* d_in, const int* in_sizes, int n_in,
                              void* d_out, int out_size, void* d_ws, size_t ws_size,
                              hipStream_t stream) {
    const float* x = (const float*)d_in[0];
    int N = in_sizes[0] / DD;            // 10000
    int k = out_size / (2 * N);          // 9
    if (k > KOUTMAX) k = KOUTMAX;

    char* ws = (char*)d_ws;
    double* partial = (double*)ws;                        // 409600 B
    double* rn      = (double*)(ws + 409600);             // 4096 B
    double* w       = (double*)(ws + 413696);             // 4096 B
    float*  rnf     = (float*) (ws + 417792);             // 2048 B
    double* sq      = (double*)(ws + 419840);             // 80000 B
    float*  sqf     = (float*) (ws + 499840);             // 40000 B
    int*    cand    = (int*)   (ws + 539840);             // N*96*4 = 3.84 MB

    int rpb = (N + NBLKA - 1) / NBLKA;
    hipLaunchKernelGGL(colsum_partial, dim3(NBLKA), dim3(256), 0, stream, x, partial, N, rpb);
    hipLaunchKernelGGL(colnorm_finish, dim3(1), dim3(512), 0, stream, partial, rn, w, rnf, NBLKA);
    hipLaunchKernelGGL(row_sq, dim3(N), dim3(256), 0, stream, x, rn, sq, sqf, N);

    int nrow = (N + PM - 1) / PM;        // 79
    int ncol = (N + PN - 1) / PN;        // 79
    hipLaunchKernelGGL(gemm_prefilter, dim3(nrow, CSPLIT), dim3(256), 0, stream,
                       x, rnf, sqf, cand, N, ncol);

    hipLaunchKernelGGL(rescore_topk, dim3((N + 3) / 4), dim3(256), 0, stream,
                       x, w, sq, cand, (int*)d_out, N, k);
}

// Round 6
// 1338.405 us; speedup vs baseline: 7.0084x; 1.9015x over previous
//
#include <hip/hip_runtime.h>
#include <math.h>

#define DD 512
#define NBLKA 100

#define PM 128          // prefilter tile rows
#define PN 128          // prefilter tile cols
#define KB 32           // k-chunk (one MFMA K per chunk)
#define ASTRIDE 40      // shorts per LDS row: 32 + 8 pad (80 B, 16B-aligned, bank-balanced)
#define CSPLIT 6        // column splits
#define NC 16           // candidates kept per row per split
#define PBUF 16         // push buffer per row
#define NCTOT (CSPLIT*NC)   // 96 candidates per row total
#define KOUTMAX 16

typedef __attribute__((ext_vector_type(8))) short bf16x8;   // 8 bf16 = 4 VGPR
typedef __attribute__((ext_vector_type(4))) float f32x4;    // MFMA 16x16 accumulator

static __device__ __forceinline__ unsigned short f2bf(float f) {
    unsigned u = __float_as_uint(f);
    u += 0x7fff + ((u >> 16) & 1);      // round-to-nearest-even
    return (unsigned short)(u >> 16);
}

// ---------------- Kernel A1: partial column sums of x^2 (fp64, deterministic) ----------------
__global__ void colsum_partial(const float* __restrict__ x, double* __restrict__ partial,
                               int N, int rows_per_block) {
    int b = blockIdx.x;
    int t = threadIdx.x;
    int r0 = b * rows_per_block;
    int r1 = min(r0 + rows_per_block, N);
    double s0 = 0.0, s1 = 0.0;
    for (int r = r0; r < r1; ++r) {
        float v0 = x[(size_t)r * DD + t];
        float v1 = x[(size_t)r * DD + t + 256];
        s0 += (double)v0 * (double)v0;
        s1 += (double)v1 * (double)v1;
    }
    partial[(size_t)b * DD + t]       = s0;
    partial[(size_t)b * DD + t + 256] = s1;
}

// ---------------- Kernel A2: rn=1/max(sqrt(s),eps) fp64, w=rn*rn fp64 ----------------
__global__ void colnorm_finish(const double* __restrict__ partial, double* __restrict__ rn,
                               double* __restrict__ w, int nblk) {
    int c = threadIdx.x;                 // 512 threads
    double s = 0.0;
    for (int b = 0; b < nblk; ++b) s += partial[(size_t)b * DD + c];
    double n = fmax(sqrt(s), 1e-12);
    double r = 1.0 / n;
    rn[c]  = r;
    w[c]   = r * r;
}

// ---------------- Kernel B: sq[i] fp64, sqf[i] fp32, xnbf[i][:] bf16 ----------------
__global__ void row_sq(const float* __restrict__ x, const double* __restrict__ rn,
                       double* __restrict__ sq, float* __restrict__ sqf,
                       unsigned short* __restrict__ xnbf, int N) {
    int i = blockIdx.x;
    int t = threadIdx.x;
    double a0 = (double)x[(size_t)i * DD + t]       * rn[t];
    double a1 = (double)x[(size_t)i * DD + t + 256] * rn[t + 256];
    xnbf[(size_t)i * DD + t]       = f2bf((float)a0);
    xnbf[(size_t)i * DD + t + 256] = f2bf((float)a1);
    double local = a0 * a0 + a1 * a1;
    __shared__ double red[256];
    red[t] = local;
    __syncthreads();
    for (int off = 128; off > 0; off >>= 1) {
        if (t < off) red[t] += red[t + off];
        __syncthreads();
    }
    if (t == 0) { sq[i] = red[0]; sqf[i] = (float)red[0]; }
}

// ---------------- Kernel C: bf16 MFMA 128x128 prefilter + per-row top-16 ----------------
// 4 waves in 2x2; each wave: 4x4 grid of 16x16x32 MFMA (64x64 strip).
// A frag: m=lane&15, k=quad*8+j ; C/D: row=quad*4+reg, col=lane&15 (guide §3, HW-verified).
__global__ __launch_bounds__(256, 2) void gemm_prefilter(
    const unsigned short* __restrict__ xnbf,
    const float* __restrict__ sqf, int* __restrict__ cand, int N, int ntileN)
{
    __shared__ unsigned short A_s[PM][ASTRIDE];   // 10240 B
    __shared__ unsigned short B_s[PN][ASTRIDE];   // 10240 B
    __shared__ float Ls[PM][NC + 1];              // 8704 B
    __shared__ int   Li[PM][NC + 1];              // 8704 B
    __shared__ float Bsc[PM][PBUF + 1];           // 8704 B
    __shared__ int   Bid[PM][PBUF + 1];           // 8704 B
    __shared__ float sqi_s[PM];
    __shared__ float sqj_s[PN];
    __shared__ float thr_s[PM];
    __shared__ int   cnt_s[PM];
    __shared__ int   flag_s;                      // total ~57.4 KB

    const int t      = threadIdx.x;
    const int lane15 = t & 15;
    const int quad   = (t >> 4) & 3;
    const int wave   = t >> 6;
    const int wr     = (wave >> 1) * 64;    // wave row origin in tile
    const int wc     = (wave & 1) * 64;     // wave col origin in tile
    const int row0   = blockIdx.x * PM;
    const int split  = blockIdx.y;

    if (t == 0) flag_s = 0;
    if (t < PM) {
        int i = row0 + t;
        sqi_s[t] = (i < N) ? sqf[i] : 0.f;
        thr_s[t] = __builtin_inff();
        cnt_s[t] = 0;
        for (int m = 0; m < NC; ++m) { Ls[t][m] = __builtin_inff(); Li[t][m] = 0x7fffffff; }
    }

    f32x4 acc[4][4];

    for (int tile = split; tile < ntileN; tile += CSPLIT) {
        int col0 = tile * PN;
        __syncthreads();
        if (t < PN) {
            int j = col0 + t;
            sqj_s[t] = (j < N) ? sqf[j] : __builtin_inff();
        }
#pragma unroll
        for (int mt = 0; mt < 4; ++mt)
#pragma unroll
            for (int nt = 0; nt < 4; ++nt)
                acc[mt][nt] = (f32x4){0.f, 0.f, 0.f, 0.f};

#pragma unroll 1
        for (int kc = 0; kc < DD; kc += KB) {
            __syncthreads();   // previous chunk's frag reads done
            // stage A/B chunk: 128 rows x 32 bf16 each; 16B-chunk XOR swizzle (c ^ (row&3))
#pragma unroll
            for (int l = 0; l < 2; ++l) {
                int e = t + l * 256;
                int r = e >> 2, c = e & 3;
                int cs = c ^ (r & 3);
                int gi = row0 + r;
                uint4 va = make_uint4(0u, 0u, 0u, 0u);
                if (gi < N) va = *(const uint4*)&xnbf[(size_t)gi * DD + kc + c * 8];
                *(uint4*)&A_s[r][cs * 8] = va;
                int gj = col0 + r;
                uint4 vb = make_uint4(0u, 0u, 0u, 0u);
                if (gj < N) vb = *(const uint4*)&xnbf[(size_t)gj * DD + kc + c * 8];
                *(uint4*)&B_s[r][cs * 8] = vb;
            }
            __syncthreads();   // staged data visible
            bf16x8 af[4], bfg[4];
#pragma unroll
            for (int mt = 0; mt < 4; ++mt) {
                int r = wr + mt * 16 + lane15;
                af[mt] = *(const bf16x8*)&A_s[r][(quad ^ (r & 3)) * 8];
            }
#pragma unroll
            for (int nt = 0; nt < 4; ++nt) {
                int cl = wc + nt * 16 + lane15;
                bfg[nt] = *(const bf16x8*)&B_s[cl][(quad ^ (cl & 3)) * 8];
            }
#pragma unroll
            for (int mt = 0; mt < 4; ++mt)
#pragma unroll
                for (int nt = 0; nt < 4; ++nt)
                    acc[mt][nt] = __builtin_amdgcn_mfma_f32_16x16x32_bf16(
                        af[mt], bfg[nt], acc[mt][nt], 0, 0, 0);
        }
        // epilogue: scores in place  s = (sq_i - 2g) + sq_j  (fp32; prefilter only)
#pragma unroll
        for (int mt = 0; mt < 4; ++mt)
#pragma unroll
            for (int nt = 0; nt < 4; ++nt)
#pragma unroll
                for (int reg = 0; reg < 4; ++reg) {
                    int rl = wr + mt * 16 + quad * 4 + reg;
                    int cl = wc + nt * 16 + lane15;
                    float g = acc[mt][nt][reg];
                    acc[mt][nt][reg] = (sqi_s[rl] - 2.f * g) + sqj_s[cl];
                }

        // ---- push/merge rounds; static acc indexing; race-free 4-barrier protocol ----
        unsigned long long done = 0ull;   // bit set = handled (stored or rejected)
        for (;;) {
            // PUSH
#pragma unroll
            for (int mt = 0; mt < 4; ++mt)
#pragma unroll
                for (int reg = 0; reg < 4; ++reg) {
                    int rl = wr + mt * 16 + quad * 4 + reg;
                    float th = thr_s[rl];
#pragma unroll
                    for (int nt = 0; nt < 4; ++nt) {
                        const unsigned long long bit = 1ull << (mt * 16 + nt * 4 + reg);
                        if (!(done & bit)) {
                            float s = acc[mt][nt][reg];
                            int   j = col0 + wc + nt * 16 + lane15;
                            if (j < N && s <= th) {
                                int pos = atomicAdd(&cnt_s[rl], 1);
                                if (pos < PBUF) {
                                    Bsc[rl][pos] = s;
                                    Bid[rl][pos] = j;
                                    done |= bit;
                                }
                            } else {
                                done |= bit;   // threshold only tightens -> final reject
                            }
                        }
                    }
                }
            if (done != ~0ull) flag_s = 1;   // benign same-value race
            __syncthreads();                 // B1: buffer + flag visible
            // MERGE
            if (t < PM) {
                int c = cnt_s[t];
                if (c > PBUF) c = PBUF;
                cnt_s[t] = 0;
                for (int m = 0; m < c; ++m) {
                    float s = Bsc[t][m];
                    int   j = Bid[t][m];
                    float ws = Ls[t][NC - 1]; int wj = Li[t][NC - 1];
                    if (s < ws || (s == ws && j < wj)) {
                        int pos = NC - 1;
                        while (pos > 0) {
                            float ps = Ls[t][pos - 1]; int pj = Li[t][pos - 1];
                            if (!(s < ps || (s == ps && j < pj))) break;
                            Ls[t][pos] = ps; Li[t][pos] = pj;
                            --pos;
                        }
                        Ls[t][pos] = s; Li[t][pos] = j;
                    }
                }
                thr_s[t] = Ls[t][NC - 1];
            }
            __syncthreads();                 // B2: merge results visible
            int go = flag_s;
            __syncthreads();                 // B3: all reads of flag done
            if (t == 0) flag_s = 0;
            __syncthreads();                 // B4: reset visible before next writes
            if (!go) break;                  // uniform across the block
        }
    }
    // write this split's 16 candidates per row
    if (t < PM) {
        int i = row0 + t;
        if (i < N) {
            for (int m = 0; m < NC; ++m)
                cand[(size_t)i * NCTOT + split * NC + m] = Li[t][m];
        }
    }
}

// ---------------- Kernel D: exact fp64 rescore of 96 candidates/row + top-k ----------------
__global__ __launch_bounds__(256) void rescore_topk(
    const float* __restrict__ x, const double* __restrict__ w,
    const double* __restrict__ sq, const int* __restrict__ cand,
    int* __restrict__ out, int N, int k)
{
    int lane = threadIdx.x & 63;
    int wid  = threadIdx.x >> 6;
    int i = blockIdx.x * 4 + wid;
    if (i >= N) return;

    double aw[8];
#pragma unroll
    for (int c = 0; c < 8; ++c) {
        int d = lane + 64 * c;
        aw[c] = (double)x[(size_t)i * DD + d] * w[d];
    }
    double sqi = sq[i];

    double bs[KOUTMAX];
    int    bj[KOUTMAX];
    for (int r = 0; r < k; ++r) { bs[r] = __builtin_inf(); bj[r] = 0x7fffffff; }

    size_t base = (size_t)i * NCTOT;
    for (int m = 0; m < NCTOT; m += 2) {
        int j0 = cand[base + m];
        int j1 = cand[base + m + 1];
        const float* p0 = &x[(size_t)j0 * DD + lane];
        const float* p1 = &x[(size_t)j1 * DD + lane];
        float v0[8], v1[8];
#pragma unroll
        for (int c = 0; c < 8; ++c) v0[c] = p0[64 * c];
#pragma unroll
        for (int c = 0; c < 8; ++c) v1[c] = p1[64 * c];
        double d0 = 0.0, d1 = 0.0;
#pragma unroll
        for (int c = 0; c < 8; ++c) d0 = fma(aw[c], (double)v0[c], d0);
#pragma unroll
        for (int c = 0; c < 8; ++c) d1 = fma(aw[c], (double)v1[c], d1);
#pragma unroll
        for (int off = 32; off > 0; off >>= 1) {
            d0 += __shfl_xor(d0, off, 64);
            d1 += __shfl_xor(d1, off, 64);
        }
        double s0 = (sqi - 2.0 * d0) + sq[j0];
        double s1 = (sqi - 2.0 * d1) + sq[j1];
#pragma unroll 1
        for (int pick = 0; pick < 2; ++pick) {
            double s = pick ? s1 : s0;
            int    j = pick ? j1 : j0;
            if (s < bs[k - 1] || (s == bs[k - 1] && j < bj[k - 1])) {
                int pos = k - 1;
                while (pos > 0) {
                    double ps = bs[pos - 1]; int pj = bj[pos - 1];
                    if (!(s < ps || (s == ps && j < pj))) break;
                    bs[pos] = ps; bj[pos] = pj;
                    --pos;
                }
                bs[pos] = s; bj[pos] = j;
            }
        }
    }
    if (lane == 0) {
        for (int r = 0; r < k; ++r) {
            out[(size_t)i * k + r]                 = bj[r];
            out[(size_t)N * k + (size_t)i * k + r] = i;
        }
    }
}

extern "C" void kernel_launch(void* const* d_in, const int* in_sizes, int n_in,
                              void* d_out, int out_size, void* d_ws, size_t ws_size,
                              hipStream_t stream) {
    const float* x = (const float*)d_in[0];
    int N = in_sizes[0] / DD;            // 10000
    int k = out_size / (2 * N);          // 9
    if (k > KOUTMAX) k = KOUTMAX;

    char* ws = (char*)d_ws;
    double*         partial = (double*)ws;                       // 409600 B
    double*         rn      = (double*)(ws + 409600);            // 4096 B
    double*         w       = (double*)(ws + 413696);            // 4096 B
    double*         sq      = (double*)(ws + 417792);            // 80000 B
    float*          sqf     = (float*) (ws + 497792);            // 40000 B
    unsigned short* xnbf    = (unsigned short*)(ws + 537792);    // N*512*2 = 10.24 MB
    int*            cand    = (int*)   (ws + 10777792);          // N*96*4  = 3.84 MB

    int rpb = (N + NBLKA - 1) / NBLKA;
    hipLaunchKernelGGL(colsum_partial, dim3(NBLKA), dim3(256), 0, stream, x, partial, N, rpb);
    hipLaunchKernelGGL(colnorm_finish, dim3(1), dim3(512), 0, stream, partial, rn, w, NBLKA);
    hipLaunchKernelGGL(row_sq, dim3(N), dim3(256), 0, stream, x, rn, sq, sqf, xnbf, N);

    int nrow = (N + PM - 1) / PM;        // 79
    int ncol = (N + PN - 1) / PN;        // 79
    hipLaunchKernelGGL(gemm_prefilter, dim3(nrow, CSPLIT), dim3(256), 0, stream,
                       xnbf, sqf, cand, N, ncol);

    hipLaunchKernelGGL(rescore_topk, dim3((N + 3) / 4), dim3(256), 0, stream,
                       x, w, sq, cand, (int*)d_out, N, k);
}

// Round 7
// 1276.325 us; speedup vs baseline: 7.3493x; 1.0486x over previous
//
#include <hip/hip_runtime.h>
#include <math.h>

#define DD 512
#define NBLKA 100

#define PM 128          // prefilter tile rows
#define PN 128          // prefilter tile cols
#define KB 32           // k-chunk (one MFMA K per chunk)
#define ASTRIDE 40      // shorts per LDS row: 32 + 8 pad (80 B, 16B-aligned, bank-balanced)
#define CSPLIT 6        // column splits
#define NC 16           // candidates kept per row per split
#define PBUF 8          // push buffer per row (8 -> LDS diet -> 3 blocks/CU)
#define NCTOT (CSPLIT*NC)   // 96 candidates per row total
#define KOUTMAX 16

typedef __attribute__((ext_vector_type(8))) short bf16x8;   // 8 bf16 = 4 VGPR
typedef __attribute__((ext_vector_type(4))) float f32x4;    // MFMA 16x16 accumulator

static __device__ __forceinline__ unsigned short f2bf(float f) {
    unsigned u = __float_as_uint(f);
    u += 0x7fff + ((u >> 16) & 1);      // round-to-nearest-even
    return (unsigned short)(u >> 16);
}

// ---------------- Kernel A1: partial column sums of x^2 (fp64, deterministic) ----------------
__global__ void colsum_partial(const float* __restrict__ x, double* __restrict__ partial,
                               int N, int rows_per_block) {
    int b = blockIdx.x;
    int t = threadIdx.x;
    int r0 = b * rows_per_block;
    int r1 = min(r0 + rows_per_block, N);
    double s0 = 0.0, s1 = 0.0;
    for (int r = r0; r < r1; ++r) {
        float v0 = x[(size_t)r * DD + t];
        float v1 = x[(size_t)r * DD + t + 256];
        s0 += (double)v0 * (double)v0;
        s1 += (double)v1 * (double)v1;
    }
    partial[(size_t)b * DD + t]       = s0;
    partial[(size_t)b * DD + t + 256] = s1;
}

// ---------------- Kernel A2: rn=1/max(sqrt(s),eps) fp64, w=rn*rn fp64 ----------------
__global__ void colnorm_finish(const double* __restrict__ partial, double* __restrict__ rn,
                               double* __restrict__ w, int nblk) {
    int c = threadIdx.x;                 // 512 threads
    double s = 0.0;
    for (int b = 0; b < nblk; ++b) s += partial[(size_t)b * DD + c];
    double n = fmax(sqrt(s), 1e-12);
    double r = 1.0 / n;
    rn[c]  = r;
    w[c]   = r * r;
}

// ---------------- Kernel B: sq[i] fp64, sqf[i] fp32, xnbf[i][:] bf16 ----------------
__global__ void row_sq(const float* __restrict__ x, const double* __restrict__ rn,
                       double* __restrict__ sq, float* __restrict__ sqf,
                       unsigned short* __restrict__ xnbf, int N) {
    int i = blockIdx.x;
    int t = threadIdx.x;
    double a0 = (double)x[(size_t)i * DD + t]       * rn[t];
    double a1 = (double)x[(size_t)i * DD + t + 256] * rn[t + 256];
    xnbf[(size_t)i * DD + t]       = f2bf((float)a0);
    xnbf[(size_t)i * DD + t + 256] = f2bf((float)a1);
    double local = a0 * a0 + a1 * a1;
    __shared__ double red[256];
    red[t] = local;
    __syncthreads();
    for (int off = 128; off > 0; off >>= 1) {
        if (t < off) red[t] += red[t + off];
        __syncthreads();
    }
    if (t == 0) { sq[i] = red[0]; sqf[i] = (float)red[0]; }
}

// ---------------- Kernel C: bf16 MFMA 128x128 prefilter + per-row top-16 ----------------
// 4 waves in 2x2; each wave: 4x4 grid of 16x16x32 MFMA.  Register-prefetch
// pipeline on the staging loads; 3 blocks/CU.
__global__ __launch_bounds__(256, 3) void gemm_prefilter(
    const unsigned short* __restrict__ xnbf,
    const float* __restrict__ sqf, int* __restrict__ cand, int N, int ntileN)
{
    __shared__ unsigned short A_s[PM][ASTRIDE];   // 10240 B
    __shared__ unsigned short B_s[PN][ASTRIDE];   // 10240 B
    __shared__ float Ls[PM][NC + 1];              // 8704 B
    __shared__ int   Li[PM][NC + 1];              // 8704 B
    __shared__ float Bsc[PM][PBUF + 1];           // 4608 B
    __shared__ int   Bid[PM][PBUF + 1];           // 4608 B
    __shared__ float sqi_s[PM];
    __shared__ float sqj_s[PN];
    __shared__ float thr_s[PM];
    __shared__ int   cnt_s[PM];
    __shared__ int   flag_s;                      // total ~48.2 KB -> 3 blocks/CU

    const int t      = threadIdx.x;
    const int lane15 = t & 15;
    const int quad   = (t >> 4) & 3;
    const int wave   = t >> 6;
    const int wr     = (wave >> 1) * 64;    // wave row origin in tile
    const int wc     = (wave & 1) * 64;     // wave col origin in tile
    const int row0   = blockIdx.x * PM;
    const int split  = blockIdx.y;

    // staging geometry for this thread (constant across chunks)
    const int sr0 = t >> 2, sc0 = t & 3;          // l=0: row, 16B-chunk
    const int sr1 = sr0 + 64, sc1 = sc0;          // l=1
    const int gi0 = row0 + sr0, gi1 = row0 + sr1;

    if (t == 0) flag_s = 0;
    if (t < PM) {
        int i = row0 + t;
        sqi_s[t] = (i < N) ? sqf[i] : 0.f;
        thr_s[t] = __builtin_inff();
        cnt_s[t] = 0;
        for (int m = 0; m < NC; ++m) { Ls[t][m] = __builtin_inff(); Li[t][m] = 0x7fffffff; }
    }

    f32x4 acc[4][4];

    for (int tile = split; tile < ntileN; tile += CSPLIT) {
        int col0 = tile * PN;
        int gj0 = col0 + sr0, gj1 = col0 + sr1;
        __syncthreads();
        if (t < PN) {
            int j = col0 + t;
            sqj_s[t] = (j < N) ? sqf[j] : __builtin_inff();
        }
#pragma unroll
        for (int mt = 0; mt < 4; ++mt)
#pragma unroll
            for (int nt = 0; nt < 4; ++nt)
                acc[mt][nt] = (f32x4){0.f, 0.f, 0.f, 0.f};

        // preload chunk 0 into registers
        const uint4 zv = make_uint4(0u, 0u, 0u, 0u);
        uint4 va0 = zv, va1 = zv, vb0 = zv, vb1 = zv;
        if (gi0 < N) va0 = *(const uint4*)&xnbf[(size_t)gi0 * DD + sc0 * 8];
        if (gi1 < N) va1 = *(const uint4*)&xnbf[(size_t)gi1 * DD + sc1 * 8];
        if (gj0 < N) vb0 = *(const uint4*)&xnbf[(size_t)gj0 * DD + sc0 * 8];
        if (gj1 < N) vb1 = *(const uint4*)&xnbf[(size_t)gj1 * DD + sc1 * 8];

#pragma unroll 1
        for (int kc = 0; kc < DD; kc += KB) {
            __syncthreads();   // previous chunk's frag reads (or prev tile's selection) done
            // write current chunk from registers; 16B-chunk XOR swizzle (c ^ (row&3))
            *(uint4*)&A_s[sr0][(sc0 ^ (sr0 & 3)) * 8] = va0;
            *(uint4*)&A_s[sr1][(sc1 ^ (sr1 & 3)) * 8] = va1;
            *(uint4*)&B_s[sr0][(sc0 ^ (sr0 & 3)) * 8] = vb0;
            *(uint4*)&B_s[sr1][(sc1 ^ (sr1 & 3)) * 8] = vb1;
            // prefetch next chunk (latency hides behind MFMA + next barrier)
            if (kc + KB < DD) {
                int koff = kc + KB;
                va0 = zv; va1 = zv; vb0 = zv; vb1 = zv;
                if (gi0 < N) va0 = *(const uint4*)&xnbf[(size_t)gi0 * DD + koff + sc0 * 8];
                if (gi1 < N) va1 = *(const uint4*)&xnbf[(size_t)gi1 * DD + koff + sc1 * 8];
                if (gj0 < N) vb0 = *(const uint4*)&xnbf[(size_t)gj0 * DD + koff + sc0 * 8];
                if (gj1 < N) vb1 = *(const uint4*)&xnbf[(size_t)gj1 * DD + koff + sc1 * 8];
            }
            __syncthreads();   // staged data visible
            bf16x8 af[4], bfg[4];
#pragma unroll
            for (int mt = 0; mt < 4; ++mt) {
                int r = wr + mt * 16 + lane15;
                af[mt] = *(const bf16x8*)&A_s[r][(quad ^ (r & 3)) * 8];
            }
#pragma unroll
            for (int nt = 0; nt < 4; ++nt) {
                int cl = wc + nt * 16 + lane15;
                bfg[nt] = *(const bf16x8*)&B_s[cl][(quad ^ (cl & 3)) * 8];
            }
#pragma unroll
            for (int mt = 0; mt < 4; ++mt)
#pragma unroll
                for (int nt = 0; nt < 4; ++nt)
                    acc[mt][nt] = __builtin_amdgcn_mfma_f32_16x16x32_bf16(
                        af[mt], bfg[nt], acc[mt][nt], 0, 0, 0);
        }
        // epilogue: scores in place  s = (sq_i - 2g) + sq_j  (fp32; prefilter only)
#pragma unroll
        for (int mt = 0; mt < 4; ++mt)
#pragma unroll
            for (int nt = 0; nt < 4; ++nt)
#pragma unroll
                for (int reg = 0; reg < 4; ++reg) {
                    int rl = wr + mt * 16 + quad * 4 + reg;
                    int cl = wc + nt * 16 + lane15;
                    float g = acc[mt][nt][reg];
                    acc[mt][nt][reg] = (sqi_s[rl] - 2.f * g) + sqj_s[cl];
                }

        // ---- push/merge rounds; static acc indexing; race-free 4-barrier protocol ----
        unsigned long long done = 0ull;   // bit set = handled (stored or rejected)
        for (;;) {
            // PUSH
#pragma unroll
            for (int mt = 0; mt < 4; ++mt)
#pragma unroll
                for (int reg = 0; reg < 4; ++reg) {
                    int rl = wr + mt * 16 + quad * 4 + reg;
                    float th = thr_s[rl];
#pragma unroll
                    for (int nt = 0; nt < 4; ++nt) {
                        const unsigned long long bit = 1ull << (mt * 16 + nt * 4 + reg);
                        if (!(done & bit)) {
                            float s = acc[mt][nt][reg];
                            int   j = col0 + wc + nt * 16 + lane15;
                            if (j < N && s <= th) {
                                int pos = atomicAdd(&cnt_s[rl], 1);
                                if (pos < PBUF) {
                                    Bsc[rl][pos] = s;
                                    Bid[rl][pos] = j;
                                    done |= bit;
                                }
                            } else {
                                done |= bit;   // threshold only tightens -> final reject
                            }
                        }
                    }
                }
            if (done != ~0ull) flag_s = 1;   // benign same-value race
            __syncthreads();                 // B1: buffer + flag visible
            // MERGE
            if (t < PM) {
                int c = cnt_s[t];
                if (c > PBUF) c = PBUF;
                cnt_s[t] = 0;
                for (int m = 0; m < c; ++m) {
                    float s = Bsc[t][m];
                    int   j = Bid[t][m];
                    float ws = Ls[t][NC - 1]; int wj = Li[t][NC - 1];
                    if (s < ws || (s == ws && j < wj)) {
                        int pos = NC - 1;
                        while (pos > 0) {
                            float ps = Ls[t][pos - 1]; int pj = Li[t][pos - 1];
                            if (!(s < ps || (s == ps && j < pj))) break;
                            Ls[t][pos] = ps; Li[t][pos] = pj;
                            --pos;
                        }
                        Ls[t][pos] = s; Li[t][pos] = j;
                    }
                }
                thr_s[t] = Ls[t][NC - 1];
            }
            __syncthreads();                 // B2: merge results visible
            int go = flag_s;
            __syncthreads();                 // B3: all reads of flag done
            if (t == 0) flag_s = 0;
            __syncthreads();                 // B4: reset visible before next writes
            if (!go) break;                  // uniform across the block
        }
    }
    // write this split's 16 candidates per row
    if (t < PM) {
        int i = row0 + t;
        if (i < N) {
            for (int m = 0; m < NC; ++m)
                cand[(size_t)i * NCTOT + split * NC + m] = Li[t][m];
        }
    }
}

// ---------------- Kernel D: exact fp64 rescore of 96 candidates/row + top-k ----------------
__global__ __launch_bounds__(256) void rescore_topk(
    const float* __restrict__ x, const double* __restrict__ w,
    const double* __restrict__ sq, const int* __restrict__ cand,
    int* __restrict__ out, int N, int k)
{
    int lane = threadIdx.x & 63;
    int wid  = threadIdx.x >> 6;
    int i = blockIdx.x * 4 + wid;
    if (i >= N) return;

    double aw[8];
#pragma unroll
    for (int c = 0; c < 8; ++c) {
        int d = lane + 64 * c;
        aw[c] = (double)x[(size_t)i * DD + d] * w[d];
    }
    double sqi = sq[i];

    double bs[KOUTMAX];
    int    bj[KOUTMAX];
    for (int r = 0; r < k; ++r) { bs[r] = __builtin_inf(); bj[r] = 0x7fffffff; }

    size_t base = (size_t)i * NCTOT;
    for (int m = 0; m < NCTOT; m += 2) {
        int j0 = cand[base + m];
        int j1 = cand[base + m + 1];
        const float* p0 = &x[(size_t)j0 * DD + lane];
        const float* p1 = &x[(size_t)j1 * DD + lane];
        float v0[8], v1[8];
#pragma unroll
        for (int c = 0; c < 8; ++c) v0[c] = p0[64 * c];
#pragma unroll
        for (int c = 0; c < 8; ++c) v1[c] = p1[64 * c];
        double d0 = 0.0, d1 = 0.0;
#pragma unroll
        for (int c = 0; c < 8; ++c) d0 = fma(aw[c], (double)v0[c], d0);
#pragma unroll
        for (int c = 0; c < 8; ++c) d1 = fma(aw[c], (double)v1[c], d1);
#pragma unroll
        for (int off = 32; off > 0; off >>= 1) {
            d0 += __shfl_xor(d0, off, 64);
            d1 += __shfl_xor(d1, off, 64);
        }
        double s0 = (sqi - 2.0 * d0) + sq[j0];
        double s1 = (sqi - 2.0 * d1) + sq[j1];
#pragma unroll 1
        for (int pick = 0; pick < 2; ++pick) {
            double s = pick ? s1 : s0;
            int    j = pick ? j1 : j0;
            if (s < bs[k - 1] || (s == bs[k - 1] && j < bj[k - 1])) {
                int pos = k - 1;
                while (pos > 0) {
                    double ps = bs[pos - 1]; int pj = bj[pos - 1];
                    if (!(s < ps || (s == ps && j < pj))) break;
                    bs[pos] = ps; bj[pos] = pj;
                    --pos;
                }
                bs[pos] = s; bj[pos] = j;
            }
        }
    }
    if (lane == 0) {
        for (int r = 0; r < k; ++r) {
            out[(size_t)i * k + r]                 = bj[r];
            out[(size_t)N * k + (size_t)i * k + r] = i;
        }
    }
}

extern "C" void kernel_launch(void* const* d_in, const int* in_sizes, int n_in,
                              void* d_out, int out_size, void* d_ws, size_t ws_size,
                              hipStream_t stream) {
    const float* x = (const float*)d_in[0];
    int N = in_sizes[0] / DD;            // 10000
    int k = out_size / (2 * N);          // 9
    if (k > KOUTMAX) k = KOUTMAX;

    char* ws = (char*)d_ws;
    double*         partial = (double*)ws;                       // 409600 B
    double*         rn      = (double*)(ws + 409600);            // 4096 B
    double*         w       = (double*)(ws + 413696);            // 4096 B
    double*         sq      = (double*)(ws + 417792);            // 80000 B
    float*          sqf     = (float*) (ws + 497792);            // 40000 B
    unsigned short* xnbf    = (unsigned short*)(ws + 537792);    // N*512*2 = 10.24 MB
    int*            cand    = (int*)   (ws + 10777792);          // N*96*4  = 3.84 MB

    int rpb = (N + NBLKA - 1) / NBLKA;
    hipLaunchKernelGGL(colsum_partial, dim3(NBLKA), dim3(256), 0, stream, x, partial, N, rpb);
    hipLaunchKernelGGL(colnorm_finish, dim3(1), dim3(512), 0, stream, partial, rn, w, NBLKA);
    hipLaunchKernelGGL(row_sq, dim3(N), dim3(256), 0, stream, x, rn, sq, sqf, xnbf, N);

    int nrow = (N + PM - 1) / PM;        // 79
    int ncol = (N + PN - 1) / PN;        // 79
    hipLaunchKernelGGL(gemm_prefilter, dim3(nrow, CSPLIT), dim3(256), 0, stream,
                       xnbf, sqf, cand, N, ncol);

    hipLaunchKernelGGL(rescore_topk, dim3((N + 3) / 4), dim3(256), 0, stream,
                       x, w, sq, cand, (int*)d_out, N, k);
}